// Round 8
// baseline (239.676 us; speedup 1.0000x reference)
//
#include <hip/hip_runtime.h>

typedef _Float16 f16x8 __attribute__((ext_vector_type(8)));
typedef float f32x4 __attribute__((ext_vector_type(4)));

#define CDIM 256
#define NE 1024
#define HW 4096        // H*W
#define CHW 1048576    // C*H*W
#define OUT_COS 262144 // 16*64*256
#define N_PIX 65536
#define NTH 16         // tiles per code-half (2 halves x 16 x 32 codes)
#define TAU 0.1f       // margin gate (~14 sigma of screen+quant error)

// x-stage geometry: 16 rounds x 16 dims; row = 256 px fp32 + 16B pad
#define XROW_DW 260            // 1040 B
#define XS_DW   (16 * XROW_DW) // 16640 B per buffer

// ws layout:
//   [0, 512K)      codebook hi fp16, TILED for 16x16x32 B-frags:
//                  addr = t*8192 + sub*4096 + f*512 + q*128 + n*8 + r
//                  code = t*32 + sub*16 + n, dim = f*32 + q*8 + r
//   [512K, 516K)   0.5*||c||^2 fp32
//   [516K, 524K)   0.5*||c||^2 fp64 (exact rescore)

__global__ void prep_kernel(const float* __restrict__ cb,
                            _Float16* __restrict__ hi,
                            float* __restrict__ c2f,
                            double* __restrict__ c2d) {
    int code = blockIdx.x;
    int lane = threadIdx.x; // 64 = 1 wave
    int t = code >> 5, sub = (code >> 4) & 1, n = code & 15;
    const float* row = cb + code * CDIM;
    double s = 0.0;
    #pragma unroll
    for (int i = 0; i < 4; ++i) {
        int d = i * 64 + lane;
        float x = row[d];
        s += (double)x * (double)x;
        int f = d >> 5, q = (d >> 3) & 3, r = d & 7;
        hi[(size_t)t * 8192 + sub * 4096 + f * 512 + q * 128 + n * 8 + r] =
            (_Float16)x;
    }
    #pragma unroll
    for (int off = 32; off > 0; off >>= 1)
        s += __shfl_down(s, off, 64);
    if (lane == 0) { c2f[code] = (float)(0.5 * s); c2d[code] = 0.5 * s; }
}

__device__ __forceinline__ void gl_lds16(const void* g, void* l) {
    __builtin_amdgcn_global_load_lds(
        (const __attribute__((address_space(1))) unsigned int*)g,
        (__attribute__((address_space(3))) unsigned int*)l, 16, 0, 0);
}

// Fused z+gt. Grid 512: [0,256)->z, [256,512)->gt. Block = 512 threads =
// 8 waves = 4 pixel-groups x 2 CODE-HALVES. Each wave: 64 px (FOUR
// 16x16x32 A-tiles, g=4) x 512 codes.
//
// R8 insight (R6 vs R7 PMC): chip-wide ds_read_b128 traffic is set by the
// MFMA:read ratio g. g=2 (R7) doubled LDS-pipe time to ~41 us and erased
// the occupancy win; g=4 keeps it at ~20 us but grid 512 x 4-wave blocks
// starved the CUs at 8 waves/CU (R6). Fix: split the CODE dimension
// inside the block -- 8-wave blocks, halves scan disjoint 512-code
// ranges, A staged ONCE per block (no extra HBM), both halves' B-tiles
// double-buffered. LDS 73.7 KB -> 2 blocks/CU = 16 waves/CU with g=4.
// Top-2 merge across halves is a free in-LDS step: packed int keys are
// globally ordered and code id (ch*512 folded in) fits the 10-bit field.
// Screen = hh-only f16; margin-gated sparse exact rescore (fp64) where
// global top-2 gap < TAU (~0.7%).
__launch_bounds__(512, 2)
__global__ void argmin_kernel(const float* __restrict__ Z,
                              const float* __restrict__ GT,
                              const _Float16* __restrict__ ghi,
                              const float* __restrict__ cb,
                              const float* __restrict__ c2f,
                              const double* __restrict__ c2d,
                              float* __restrict__ out_z,
                              float* __restrict__ out_gt) {
    __shared__ __align__(16) char smem[65536 + 4096 + 2048 + 2048];
    float*    xs    = (float*)smem;             // 2 x 16640 B (A-phase)
    _Float16* lbuf  = (_Float16*)smem;          // 4 x 16 KB [ch][buf] (alias)
    float*    c2s   = (float*)(smem + 65536);   // 4 KB
    int*      cand1 = (int*)(smem + 69632);     // [ch][px] best key
    int*      cand2 = (int*)(smem + 71680);     // [ch][px] 2nd key

    const int tid  = threadIdx.x;
    const int wave = tid >> 6;       // 0..7
    const int lane = tid & 63;
    const int l15  = lane & 15;
    const int quad = lane >> 4;
    const int pw   = wave & 3;       // pixel group (64 px)
    const int ch   = wave >> 2;      // code half (512 codes)
    const int inp  = blockIdx.x >> 8;
    const float* X = inp ? GT : Z;
    float* out_idx = inp ? out_gt : out_z;
    const int p0 = (blockIdx.x & 255) * 256;

    // preload c2 into LDS (4 KB)
    #pragma unroll
    for (int i = 0; i < 2; ++i)
        c2s[i * 512 + tid] = c2f[i * 512 + tid];

    // ---- A-phase: 16 rounds x 16 dims of X staged to LDS, rebuild nah.
    // One gl_lds16 per row = 256 px (64 lanes x 16 B); 2 rows per wave.
    const float* xsrc = X + (size_t)(p0 >> 12) * CHW + (p0 & 4095);

    auto stage_x = [&](int b, int fr) {
        #pragma unroll
        for (int i = 0; i < 2; ++i) {
            const int rr = wave * 2 + i;         // row in round
            const int d = fr * 16 + rr;          // global dim
            gl_lds16(xsrc + (size_t)d * HW + lane * 4,
                     xs + b * (XS_DW / 1) + rr * XROW_DW);
        }
    };

    // rebuild: lane's dims for frag f are d = f*32 + quad*8 + j, j<8.
    // round fr = 2f + (quad>>1) holds them at row rr = (quad&1)*8 + j.
    f16x8 nah[4][8];
    stage_x(0, 0);
    int xb = 0;
    #pragma unroll
    for (int fr = 0; fr < 16; ++fr) {
        __syncthreads();                 // xs[xb] ready (drains vmcnt)
        if (fr < 15) stage_x(xb ^ 1, fr + 1);
        if ((quad >> 1) == (fr & 1)) {
            const int f = fr >> 1;       // static after unroll (rule #20)
            const float* xsb = xs + xb * XS_DW;
            const int abase = (quad & 1) * 8 * XROW_DW + pw * 64 + l15;
            #pragma unroll
            for (int g = 0; g < 4; ++g) {
                f16x8 tv;
                #pragma unroll
                for (int j = 0; j < 8; ++j)
                    tv[j] = -(_Float16)xsb[abase + j * XROW_DW + g * 16];
                nah[g][f] = tv;
            }
        }
        xb ^= 1;
    }
    __syncthreads(); // all rebuilds done before lbuf overwrites xs

    int b1[4][4], b2[4][4];
    #pragma unroll
    for (int g = 0; g < 4; ++g)
        #pragma unroll
        for (int r = 0; r < 4; ++r) { b1[g][r] = 0x7fffffff; b2[g][r] = 0x7fffffff; }

    // stage this half's 16 KB B-tile = 16 x 1KB chunks, 4 per pixel-wave
    auto stage = [&](int b, int t) {
        #pragma unroll
        for (int i = 0; i < 4; ++i) {
            const int c = pw * 4 + i;
            gl_lds16(ghi + (size_t)(ch * NTH + t) * 8192 + c * 512 + lane * 8,
                     lbuf + (ch * 2 + b) * 8192 + c * 512);
        }
    };

    stage(0, 0);
    __syncthreads();

    for (int t = 0; t < NTH; ++t) {
        const int cur = t & 1;
        if (t < NTH - 1) stage(cur ^ 1, t + 1);

        #pragma unroll
        for (int sub = 0; sub < 2; ++sub) {
            const int n = ch * 512 + t * 32 + sub * 16 + l15; // global code
            const float c2 = c2s[n];
            f32x4 acc[4];
            #pragma unroll
            for (int g = 0; g < 4; ++g)
                acc[g] = (f32x4){c2, c2, c2, c2};

            #pragma unroll
            for (int f = 0; f < 8; ++f) {
                // B[k=quad*8+j][n=l15]: contiguous 16B/lane, conflict-free
                f16x8 bh = *(const f16x8*)
                    &lbuf[(ch * 2 + cur) * 8192 + sub * 4096 + f * 512 + lane * 8];
                acc[0] = __builtin_amdgcn_mfma_f32_16x16x32_f16(nah[0][f], bh, acc[0], 0, 0, 0);
                acc[1] = __builtin_amdgcn_mfma_f32_16x16x32_f16(nah[1][f], bh, acc[1], 0, 0, 0);
                acc[2] = __builtin_amdgcn_mfma_f32_16x16x32_f16(nah[2][f], bh, acc[2], 0, 0, 0);
                acc[3] = __builtin_amdgcn_mfma_f32_16x16x32_f16(nah[3][f], bh, acc[3], 0, 0, 0);
            }

            #pragma unroll
            for (int g = 0; g < 4; ++g) {
                #pragma unroll
                for (int r = 0; r < 4; ++r) {
                    int k = (__float_as_int(acc[g][r]) & 0xFFFFFC00) | n;
                    int mx = max(b1[g][r], k);      // before b1 update!
                    b2[g][r] = min(b2[g][r], mx);
                    b1[g][r] = min(b1[g][r], k);
                }
            }
        }
        __syncthreads();
    }

    // ---- cross-lane top-2: 16 cols live in l15 of each quad ----
    #pragma unroll
    for (int g = 0; g < 4; ++g) {
        #pragma unroll
        for (int r = 0; r < 4; ++r) {
            int x1 = b1[g][r], x2 = b2[g][r];
            #pragma unroll
            for (int off = 8; off > 0; off >>= 1) { // stays in 16-lane group
                int o1 = __shfl_xor(x1, off, 64);
                int o2 = __shfl_xor(x2, off, 64);
                int tt = max(x1, o1);
                x2 = min(min(x2, o2), tt);
                x1 = min(x1, o1);
            }
            if (l15 == 0) {
                const int row = quad * 4 + r;       // 16x16 C/D row (m89/m91)
                const int px = pw * 64 + g * 16 + row;
                cand1[ch * 256 + px] = x1;
                cand2[ch * 256 + px] = x2;
            }
        }
    }
    __syncthreads();

    // ---- cross-half merge + output: thread tid<256 owns pixel tid ----
    if (tid < 256) {
        const int px = tid;
        const int a1 = cand1[px],       a2 = cand2[px];
        const int c1 = cand1[256 + px], c2k = cand2[256 + px];
        const int m1 = min(a1, c1);
        const int m2 = min(min(a2, c2k), max(a1, c1));
        const int i1 = m1 & 1023, i2 = m2 & 1023;
        const float s1 = __int_as_float(m1 & 0xFFFFFC00);
        const float s2 = __int_as_float(m2 & 0xFFFFFC00);
        const int p = p0 + px;
        if ((s2 - s1) >= TAU) {
            out_idx[p] = (float)i1;
        } else {
            // sparse exact rescore (fp64), ~1% of pixels
            const float* xb2 = X + (size_t)(p >> 12) * CHW + (p & 4095);
            const float* r1 = cb + (size_t)i1 * CDIM;
            const float* r2 = cb + (size_t)i2 * CDIM;
            double d1 = 0.0, d2 = 0.0;
            #pragma unroll 4
            for (int d = 0; d < CDIM; d += 4) {
                float x0 = xb2[(size_t)(d + 0) * HW];
                float x1v = xb2[(size_t)(d + 1) * HW];
                float x2v = xb2[(size_t)(d + 2) * HW];
                float x3v = xb2[(size_t)(d + 3) * HW];
                const float4 v1 = *(const float4*)(r1 + d);
                const float4 v2 = *(const float4*)(r2 + d);
                d1 += (double)x0 * v1.x + (double)x1v * v1.y
                    + (double)x2v * v1.z + (double)x3v * v1.w;
                d2 += (double)x0 * v2.x + (double)x1v * v2.y
                    + (double)x2v * v2.z + (double)x3v * v2.w;
            }
            const double dd1 = c2d[i1] - d1;
            const double dd2 = c2d[i2] - d2;
            const int bi = (dd2 < dd1 || (dd2 == dd1 && i2 < i1)) ? i2 : i1;
            out_idx[p] = (float)bi;
        }
    }
}

// cosine over H: one block per (b,w), one thread per channel c.
__global__ void cosine_kernel(const float* __restrict__ cb,
                              const float* __restrict__ idx_z_f,
                              const float* __restrict__ idx_gt_f,
                              float* __restrict__ out_cos) {
    __shared__ int s_ig[64], s_iq[64];
    const int bw = blockIdx.x;
    const int c = threadIdx.x;
    const int b = bw >> 6, w = bw & 63;
    if (c < 64) {
        s_ig[c] = (int)idx_gt_f[b * 4096 + c * 64 + w];
    } else if (c < 128) {
        int h = c - 64;
        s_iq[h] = (int)idx_z_f[b * 4096 + h * 64 + w];
    }
    __syncthreads();
    float num = 0.f, sa = 0.f, sb = 0.f;
    #pragma unroll 1
    for (int h = 0; h < 64; h += 4) {
        float av[4], bv[4];
        #pragma unroll
        for (int u = 0; u < 4; ++u) {
            av[u] = cb[s_ig[h + u] * CDIM + c];
            bv[u] = cb[s_iq[h + u] * CDIM + c];
        }
        #pragma unroll
        for (int u = 0; u < 4; ++u) {
            num += av[u] * bv[u];
            sa += av[u] * av[u];
            sb += bv[u] * bv[u];
        }
    }
    const float nx = fmaxf(sqrtf(sa), 1e-8f);
    const float ny = fmaxf(sqrtf(sb), 1e-8f);
    out_cos[bw * CDIM + c] = num / (nx * ny);
}

extern "C" void kernel_launch(void* const* d_in, const int* in_sizes, int n_in,
                              void* d_out, int out_size, void* d_ws, size_t ws_size,
                              hipStream_t stream) {
    const float* z  = (const float*)d_in[0];
    const float* gt = (const float*)d_in[1];
    const float* cb = (const float*)d_in[2];
    float* out = (float*)d_out;

    _Float16* hi = (_Float16*)d_ws;
    float*  c2f = (float*)((char*)d_ws + 512 * 1024);
    double* c2d = (double*)((char*)d_ws + 516 * 1024);

    float* out_cos    = out;                   // (16,64,256)
    float* out_idx_gt = out + OUT_COS;         // (65536,1)
    float* out_idx_z  = out + OUT_COS + N_PIX; // (65536,1)

    prep_kernel<<<NE, 64, 0, stream>>>(cb, hi, c2f, c2d);
    argmin_kernel<<<512, 512, 0, stream>>>(z, gt, hi, cb, c2f, c2d,
                                           out_idx_z, out_idx_gt);
    cosine_kernel<<<1024, 256, 0, stream>>>(cb, out_idx_z, out_idx_gt, out_cos);
}

// Round 9
// 233.731 us; speedup vs baseline: 1.0254x; 1.0254x over previous
//
#include <hip/hip_runtime.h>

typedef _Float16 f16x8 __attribute__((ext_vector_type(8)));
typedef float f32x4 __attribute__((ext_vector_type(4)));

#define CDIM 256
#define NE 1024
#define HW 4096        // H*W
#define CHW 1048576    // C*H*W
#define OUT_COS 262144 // 16*64*256
#define N_PIX 65536
#define NT 32          // 32-code LDS tiles (2 x 16-code subtiles)
#define TAU 0.1f       // margin gate (~14 sigma of screen+quant error)

// x-stage geometry: 16 rounds x 16 dims; row = 256 px fp32 + 16B pad
#define XROW_DW 260            // 1040 B
#define XS_DW   4160           // 16 rows x 260 dw = 16640 B per buffer

// ws layout:
//   [0, 512K)      codebook hi fp16, TILED for 16x16x32 B-frags:
//                  addr = t*8192 + sub*4096 + f*512 + q*128 + n*8 + r
//                  code = t*32 + sub*16 + n, dim = f*32 + q*8 + r
//   [512K, 516K)   0.5*||c||^2 fp32
//   [516K, 524K)   0.5*||c||^2 fp64 (exact rescore)

__global__ void prep_kernel(const float* __restrict__ cb,
                            _Float16* __restrict__ hi,
                            float* __restrict__ c2f,
                            double* __restrict__ c2d) {
    int code = blockIdx.x;
    int lane = threadIdx.x; // 64 = 1 wave
    int t = code >> 5, sub = (code >> 4) & 1, n = code & 15;
    const float* row = cb + code * CDIM;
    double s = 0.0;
    #pragma unroll
    for (int i = 0; i < 4; ++i) {
        int d = i * 64 + lane;
        float x = row[d];
        s += (double)x * (double)x;
        int f = d >> 5, q = (d >> 3) & 3, r = d & 7;
        hi[(size_t)t * 8192 + sub * 4096 + f * 512 + q * 128 + n * 8 + r] =
            (_Float16)x;
    }
    #pragma unroll
    for (int off = 32; off > 0; off >>= 1)
        s += __shfl_down(s, off, 64);
    if (lane == 0) { c2f[code] = (float)(0.5 * s); c2d[code] = 0.5 * s; }
}

__device__ __forceinline__ void gl_lds16(const void* g, void* l) {
    __builtin_amdgcn_global_load_lds(
        (const __attribute__((address_space(1))) unsigned int*)g,
        (__attribute__((address_space(3))) unsigned int*)l, 16, 0, 0);
}

// Fused z+gt. Grid 512: [0,256)->z, [256,512)->gt. Block = 256 pixels,
// 4 waves x 64 pixels as FOUR 16x16x32 A-tiles (g=4: each B ds_read
// feeds 4 MFMAs -- proven best LDS ratio, R6).
//
// R9 change: counted-vmcnt pipeline (guide T4; m218 +38-73%). R6-R8 PMC
// triangulation: occupancy 18%/33%/18% all land at 120-134 us -- TLP is
// not the binding resource; the per-barrier vmcnt(0) drain is (compiler's
// __syncthreads drains the whole global_load_lds queue, ~200-900 cyc x 48
// barriers, all waves in lockstep). Now BOTH staged loops run:
//   stage(t+1) -> s_waitcnt vmcnt(4) (tile t's 4 loads done; t+1's stay
//   IN FLIGHT across the barrier) -> raw s_barrier + sched_barrier(0)
//   -> compute tile t.
// Triple buffering makes one-barrier-per-tile safe: at iter t the stage
// writes buf (t+1)%3, last read at t-2, protected by the collective
// barrier at t-1. Nothing VMEM issues between stage and waitcnt, so the
// count is exact (older c2s stragglers only make it conservative).
// LDS: 3x16.6KB xs aliased by 3x16KB lbuf + c2s + cand = 55KB, 2 blk/CU.
// Screen = hh-only; per-lane top-2 packed int keys; margin-gated sparse
// exact rescore (fp64) where top-2 gap < TAU (~0.7%).
__launch_bounds__(256, 2)
__global__ void argmin_kernel(const float* __restrict__ Z,
                              const float* __restrict__ GT,
                              const _Float16* __restrict__ ghi,
                              const float* __restrict__ cb,
                              const float* __restrict__ c2f,
                              const double* __restrict__ c2d,
                              float* __restrict__ out_z,
                              float* __restrict__ out_gt) {
    __shared__ __align__(16) char smem[55040];
    float*    xs   = (float*)smem;              // 3 x 16640 B (A-phase)
    _Float16* lbuf = (_Float16*)smem;           // 3 x 16 KB (main, alias)
    float*    c2s  = (float*)(smem + 49920);    // 4 KB
    int*      cand = (int*)(smem + 54016);      // 4 waves x 64

    const int wave = threadIdx.x >> 6;
    const int lane = threadIdx.x & 63;
    const int l15 = lane & 15;
    const int quad = lane >> 4;
    const int half = blockIdx.x >> 8;
    const float* X = half ? GT : Z;
    float* out_idx = half ? out_gt : out_z;
    const int p0 = (blockIdx.x & 255) * 256;

    // preload c2 into LDS (4 KB); ds_writes drained by the full
    // __syncthreads at the A-phase/main-loop boundary
    #pragma unroll
    for (int i = 0; i < 4; ++i)
        c2s[i * 256 + threadIdx.x] = c2f[i * 256 + threadIdx.x];

    // ---- A-phase: 16 rounds x 16 dims of X staged to LDS, rebuild nah.
    const float* xsrc = X + (size_t)(p0 >> 12) * CHW + (p0 & 4095);

    // round fr stages dims [fr*16, fr*16+16): row rr <- dim fr*16+rr
    auto stage_x = [&](int b, int fr) {
        #pragma unroll
        for (int i = 0; i < 4; ++i) {
            const int rr = wave * 4 + i;
            const int d = fr * 16 + rr;
            gl_lds16(xsrc + (size_t)d * HW + lane * 4,
                     xs + b * XS_DW + rr * XROW_DW);
        }
    };

    // rebuild: lane's dims for frag f are d = f*32 + quad*8 + j, j<8.
    // round fr = 2f + (quad>>1) holds them at row rr = (quad&1)*8 + j.
    f16x8 nah[4][8];
    stage_x(0, 0);
    #pragma unroll
    for (int fr = 0; fr < 16; ++fr) {
        if (fr < 15) {
            stage_x((fr + 1) % 3, fr + 1);
            asm volatile("s_waitcnt vmcnt(4)" ::: "memory");
        } else {
            asm volatile("s_waitcnt vmcnt(0)" ::: "memory");
        }
        __builtin_amdgcn_s_barrier();
        __builtin_amdgcn_sched_barrier(0);
        if ((quad >> 1) == (fr & 1)) {
            const int f = fr >> 1;       // static after unroll (rule #20)
            const float* xsb = xs + (fr % 3) * XS_DW;
            const int abase = (quad & 1) * 8 * XROW_DW + wave * 64 + l15;
            #pragma unroll
            for (int g = 0; g < 4; ++g) {
                f16x8 tv;
                #pragma unroll
                for (int j = 0; j < 8; ++j)
                    tv[j] = -(_Float16)xsb[abase + j * XROW_DW + g * 16];
                nah[g][f] = tv;
            }
        }
    }
    __syncthreads(); // full drain (incl. c2s ds_writes) before lbuf aliases xs

    int b1[4][4], b2[4][4];
    #pragma unroll
    for (int g = 0; g < 4; ++g)
        #pragma unroll
        for (int r = 0; r < 4; ++r) { b1[g][r] = 0x7fffffff; b2[g][r] = 0x7fffffff; }

    // stage 16 KB B-tile = 16 x 1KB chunks, 4 per wave
    auto stage = [&](int b, int t) {
        #pragma unroll
        for (int i = 0; i < 4; ++i) {
            const int c = wave * 4 + i;
            gl_lds16(ghi + (size_t)t * 8192 + c * 512 + lane * 8,
                     lbuf + b * 8192 + c * 512);
        }
    };

    stage(0, 0);
    int cur = 0;
    for (int t = 0; t < NT; ++t) {
        const int nxt = (cur == 2) ? 0 : cur + 1;
        if (t < NT - 1) {
            stage(nxt, t + 1);
            asm volatile("s_waitcnt vmcnt(4)" ::: "memory");
        } else {
            asm volatile("s_waitcnt vmcnt(0)" ::: "memory");
        }
        __builtin_amdgcn_s_barrier();
        __builtin_amdgcn_sched_barrier(0);

        #pragma unroll
        for (int sub = 0; sub < 2; ++sub) {
            const int n = t * 32 + sub * 16 + l15; // this lane's code (col)
            const float c2 = c2s[n];
            f32x4 acc[4];
            #pragma unroll
            for (int g = 0; g < 4; ++g)
                acc[g] = (f32x4){c2, c2, c2, c2};

            #pragma unroll
            for (int f = 0; f < 8; ++f) {
                // B[k=quad*8+j][n=l15]: contiguous 16B/lane, conflict-free
                f16x8 bh = *(const f16x8*)
                    &lbuf[cur * 8192 + sub * 4096 + f * 512 + lane * 8];
                acc[0] = __builtin_amdgcn_mfma_f32_16x16x32_f16(nah[0][f], bh, acc[0], 0, 0, 0);
                acc[1] = __builtin_amdgcn_mfma_f32_16x16x32_f16(nah[1][f], bh, acc[1], 0, 0, 0);
                acc[2] = __builtin_amdgcn_mfma_f32_16x16x32_f16(nah[2][f], bh, acc[2], 0, 0, 0);
                acc[3] = __builtin_amdgcn_mfma_f32_16x16x32_f16(nah[3][f], bh, acc[3], 0, 0, 0);
            }

            #pragma unroll
            for (int g = 0; g < 4; ++g) {
                #pragma unroll
                for (int r = 0; r < 4; ++r) {
                    int k = (__float_as_int(acc[g][r]) & 0xFFFFFC00) | n;
                    int mx = max(b1[g][r], k);      // before b1 update!
                    b2[g][r] = min(b2[g][r], mx);
                    b1[g][r] = min(b1[g][r], k);
                }
            }
        }
        cur = nxt;
    }

    // ---- cross-lane top-2 merge: 16 cols live in l15 of each quad ----
    #pragma unroll
    for (int g = 0; g < 4; ++g) {
        #pragma unroll
        for (int r = 0; r < 4; ++r) {
            int x1 = b1[g][r], x2 = b2[g][r];
            #pragma unroll
            for (int off = 8; off > 0; off >>= 1) { // stays in 16-lane group
                int o1 = __shfl_xor(x1, off, 64);
                int o2 = __shfl_xor(x2, off, 64);
                int tt = max(x1, o1);
                x2 = min(min(x2, o2), tt);
                x1 = min(x1, o1);
            }
            if (l15 == 0) {
                const int i1 = x1 & 1023, i2 = x2 & 1023;
                const float s1 = __int_as_float(x1 & 0xFFFFFC00);
                const float s2 = __int_as_float(x2 & 0xFFFFFC00);
                const int row = quad * 4 + r;       // 16x16 C/D row (m89/m91)
                const int slot = g * 16 + row;
                const bool flag = (s2 - s1) < TAU;
                cand[wave * 64 + slot] = i1 | (i2 << 10) | (flag ? (1 << 20) : 0);
                if (!flag) out_idx[p0 + wave * 64 + slot] = (float)i1;
            }
        }
    }

    // ---- sparse exact rescore: lane ℓ owns pixel wave*64 + ℓ ----
    // (cand row is written and read by the SAME wave; compiler-inserted
    // lgkmcnt ordering suffices, as verified in R0/R2/R4/R5/R6)
    const int info = cand[wave * 64 + lane];
    if (info & (1 << 20)) {
        const int i1 = info & 1023, i2 = (info >> 10) & 1023;
        const int p = p0 + wave * 64 + lane;
        const float* xb2 = X + (size_t)(p >> 12) * CHW + (p & 4095);
        const float* r1 = cb + (size_t)i1 * CDIM;
        const float* r2 = cb + (size_t)i2 * CDIM;
        double d1 = 0.0, d2 = 0.0;
        #pragma unroll 4
        for (int d = 0; d < CDIM; d += 4) {
            float x0 = xb2[(size_t)(d + 0) * HW];
            float x1v = xb2[(size_t)(d + 1) * HW];
            float x2v = xb2[(size_t)(d + 2) * HW];
            float x3v = xb2[(size_t)(d + 3) * HW];
            const float4 v1 = *(const float4*)(r1 + d);
            const float4 v2 = *(const float4*)(r2 + d);
            d1 += (double)x0 * v1.x + (double)x1v * v1.y
                + (double)x2v * v1.z + (double)x3v * v1.w;
            d2 += (double)x0 * v2.x + (double)x1v * v2.y
                + (double)x2v * v2.z + (double)x3v * v2.w;
        }
        const double dd1 = c2d[i1] - d1;
        const double dd2 = c2d[i2] - d2;
        const int bi = (dd2 < dd1 || (dd2 == dd1 && i2 < i1)) ? i2 : i1;
        out_idx[p] = (float)bi;
    }
}

// cosine over H: one block per (b,w), one thread per channel c.
__global__ void cosine_kernel(const float* __restrict__ cb,
                              const float* __restrict__ idx_z_f,
                              const float* __restrict__ idx_gt_f,
                              float* __restrict__ out_cos) {
    __shared__ int s_ig[64], s_iq[64];
    const int bw = blockIdx.x;
    const int c = threadIdx.x;
    const int b = bw >> 6, w = bw & 63;
    if (c < 64) {
        s_ig[c] = (int)idx_gt_f[b * 4096 + c * 64 + w];
    } else if (c < 128) {
        int h = c - 64;
        s_iq[h] = (int)idx_z_f[b * 4096 + h * 64 + w];
    }
    __syncthreads();
    float num = 0.f, sa = 0.f, sb = 0.f;
    #pragma unroll 1
    for (int h = 0; h < 64; h += 4) {
        float av[4], bv[4];
        #pragma unroll
        for (int u = 0; u < 4; ++u) {
            av[u] = cb[s_ig[h + u] * CDIM + c];
            bv[u] = cb[s_iq[h + u] * CDIM + c];
        }
        #pragma unroll
        for (int u = 0; u < 4; ++u) {
            num += av[u] * bv[u];
            sa += av[u] * av[u];
            sb += bv[u] * bv[u];
        }
    }
    const float nx = fmaxf(sqrtf(sa), 1e-8f);
    const float ny = fmaxf(sqrtf(sb), 1e-8f);
    out_cos[bw * CDIM + c] = num / (nx * ny);
}

extern "C" void kernel_launch(void* const* d_in, const int* in_sizes, int n_in,
                              void* d_out, int out_size, void* d_ws, size_t ws_size,
                              hipStream_t stream) {
    const float* z  = (const float*)d_in[0];
    const float* gt = (const float*)d_in[1];
    const float* cb = (const float*)d_in[2];
    float* out = (float*)d_out;

    _Float16* hi = (_Float16*)d_ws;
    float*  c2f = (float*)((char*)d_ws + 512 * 1024);
    double* c2d = (double*)((char*)d_ws + 516 * 1024);

    float* out_cos    = out;                   // (16,64,256)
    float* out_idx_gt = out + OUT_COS;         // (65536,1)
    float* out_idx_z  = out + OUT_COS + N_PIX; // (65536,1)

    prep_kernel<<<NE, 64, 0, stream>>>(cb, hi, c2f, c2d);
    argmin_kernel<<<512, 256, 0, stream>>>(z, gt, hi, cb, c2f, c2d,
                                           out_idx_z, out_idx_gt);
    cosine_kernel<<<1024, 256, 0, stream>>>(cb, out_idx_z, out_idx_gt, out_cos);
}

// Round 10
// 228.493 us; speedup vs baseline: 1.0489x; 1.0229x over previous
//
#include <hip/hip_runtime.h>

typedef _Float16 f16x8 __attribute__((ext_vector_type(8)));
typedef float f32x4 __attribute__((ext_vector_type(4)));

#define CDIM 256
#define NE 1024
#define HW 4096        // H*W
#define CHW 1048576    // C*H*W
#define OUT_COS 262144 // 16*64*256
#define N_PIX 65536
#define NT 32          // 32-code LDS tiles (2 x 16-code subtiles)
#define TAU 0.1f       // margin gate (~14 sigma of screen+quant error)

// x-stage geometry: 16 rounds x 16 dims; row = 256 px fp32 + 16B pad
#define XROW_DW 260            // 1040 B
#define XS_DW   (16 * XROW_DW) // 4160 dw = 16640 B per buffer

// ws layout:
//   [0, 512K)      codebook hi fp16, TILED for 16x16x32 B-frags:
//                  addr = t*8192 + sub*4096 + f*512 + q*128 + n*8 + r
//                  code = t*32 + sub*16 + n, dim = f*32 + q*8 + r
//   [512K, 516K)   0.5*||c||^2 fp32
//   [516K, 524K)   0.5*||c||^2 fp64 (exact rescore)

__global__ void prep_kernel(const float* __restrict__ cb,
                            _Float16* __restrict__ hi,
                            float* __restrict__ c2f,
                            double* __restrict__ c2d) {
    int code = blockIdx.x;
    int lane = threadIdx.x; // 64 = 1 wave
    int t = code >> 5, sub = (code >> 4) & 1, n = code & 15;
    const float* row = cb + code * CDIM;
    double s = 0.0;
    #pragma unroll
    for (int i = 0; i < 4; ++i) {
        int d = i * 64 + lane;
        float x = row[d];
        s += (double)x * (double)x;
        int f = d >> 5, q = (d >> 3) & 3, r = d & 7;
        hi[(size_t)t * 8192 + sub * 4096 + f * 512 + q * 128 + n * 8 + r] =
            (_Float16)x;
    }
    #pragma unroll
    for (int off = 32; off > 0; off >>= 1)
        s += __shfl_down(s, off, 64);
    if (lane == 0) { c2f[code] = (float)(0.5 * s); c2d[code] = 0.5 * s; }
}

__device__ __forceinline__ void gl_lds16(const void* g, void* l) {
    __builtin_amdgcn_global_load_lds(
        (const __attribute__((address_space(1))) unsigned int*)g,
        (__attribute__((address_space(3))) unsigned int*)l, 16, 0, 0);
}

// Fused z+gt. Grid 512: [0,256)->z, [256,512)->gt. Block = 256 pixels,
// 4 waves x 64 pixels as FOUR 16x16x32 A-tiles (g=4, best LDS ratio).
//
// R10 change: de-phasing. R6-R9 PMC triangulation: duration tracks the
// SUM of pipe demands (matrix 33 + VALU 36 + LDS 25 + HBM 15 ~= 120) at
// both 18% and 33% occupancy, and neither counted-vmcnt nor more waves
// helped -- the pipes alternate oversubscribed/idle because barriers
// release all waves into identical phase sequences (read burst -> MFMA
// burst -> screen burst) in global lockstep. Three changes, one theory:
// (1) block-parity sub order ((bid^(bid>>3))&1 covers linear and
//     round-robin co-residency): co-resident blocks run a half-tile out
//     of phase so one block's MFMA overlaps the other's screen VALU.
//     Output bitwise identical (subs independent).
// (2) tile-top c2 prefetch: kills the per-sub ds_read->init->MFMA ramp.
// (3) v_med3_i32 screen: b2 = med3(b1,b2,k) saves 1 VALU/acc (valid
//     since b1<=b2 invariant).
// A-gather: R5/R6 structure (gl_lds width=16, 16 rounds x 16 dims).
// Screen = hh-only; margin-gated sparse exact rescore (fp64) < TAU.
__launch_bounds__(256, 2)
__global__ void argmin_kernel(const float* __restrict__ Z,
                              const float* __restrict__ GT,
                              const _Float16* __restrict__ ghi,
                              const float* __restrict__ cb,
                              const float* __restrict__ c2f,
                              const double* __restrict__ c2d,
                              float* __restrict__ out_z,
                              float* __restrict__ out_gt) {
    __shared__ __align__(16) char smem[2 * 16640 + 4096 + 1024];
    float*    xs   = (float*)smem;              // 2 x 16640 B (A-phase)
    _Float16* lbuf = (_Float16*)smem;           // 2 x 16 KB (main loop, alias)
    float*    c2s  = (float*)(smem + 33280);    // 4 KB
    int*      cand = (int*)(smem + 37376);      // 4 waves x 64

    const int wave = threadIdx.x >> 6;
    const int lane = threadIdx.x & 63;
    const int l15 = lane & 15;
    const int quad = lane >> 4;
    const int half = blockIdx.x >> 8;
    const float* X = half ? GT : Z;
    float* out_idx = half ? out_gt : out_z;
    const int p0 = (blockIdx.x & 255) * 256;
    // sub-order parity: flips for both +1 and +8 blockIdx deltas
    const int sparity = (blockIdx.x ^ (blockIdx.x >> 3)) & 1;

    // preload c2 into LDS (4 KB); ordered before first use by A-phase syncs
    #pragma unroll
    for (int i = 0; i < 4; ++i)
        c2s[i * 256 + threadIdx.x] = c2f[i * 256 + threadIdx.x];

    // ---- A-phase: stage 16-dim rounds of X into LDS, rebuild nah ----
    const float* xsrc = X + (size_t)(p0 >> 12) * CHW + (p0 & 4095);

    // round fr stages dims [fr*16, fr*16+16); row rr <- dim fr*16+rr
    auto stage_x = [&](int b, int fr) {
        #pragma unroll
        for (int i = 0; i < 4; ++i) {
            const int rr = wave * 4 + i;
            const int d = fr * 16 + rr;
            gl_lds16(xsrc + (size_t)d * HW + lane * 4,
                     xs + b * XS_DW + rr * XROW_DW);
        }
    };

    // rebuild: lane's dims for frag f are d = f*32 + quad*8 + j, j<8.
    // round fr = 2f + (quad>>1) holds them at row rr = (quad&1)*8 + j.
    f16x8 nah[4][8];
    stage_x(0, 0);
    int xb = 0;
    #pragma unroll
    for (int fr = 0; fr < 16; ++fr) {
        __syncthreads();                 // xs[xb] ready (drains vmcnt)
        if (fr < 15) stage_x(xb ^ 1, fr + 1);
        if ((quad >> 1) == (fr & 1)) {
            const int f = fr >> 1;       // static after unroll (rule #20)
            const float* xsb = xs + xb * XS_DW;
            const int abase = (quad & 1) * 8 * XROW_DW + wave * 64 + l15;
            #pragma unroll
            for (int g = 0; g < 4; ++g) {
                f16x8 tv;
                #pragma unroll
                for (int j = 0; j < 8; ++j)
                    tv[j] = -(_Float16)xsb[abase + j * XROW_DW + g * 16];
                nah[g][f] = tv;
            }
        }
        xb ^= 1;
    }
    __syncthreads(); // all rebuilds done before lbuf overwrites xs

    int b1[4][4], b2[4][4];
    #pragma unroll
    for (int g = 0; g < 4; ++g)
        #pragma unroll
        for (int r = 0; r < 4; ++r) { b1[g][r] = 0x7fffffff; b2[g][r] = 0x7fffffff; }

    // stage 16 KB B-tile = 16 x 1KB chunks, 4 per wave
    auto stage = [&](int b, int t) {
        #pragma unroll
        for (int i = 0; i < 4; ++i) {
            const int c = wave * 4 + i;
            gl_lds16(ghi + (size_t)t * 8192 + c * 512 + lane * 8,
                     lbuf + b * 8192 + c * 512);
        }
    };

    stage(0, 0);
    __syncthreads();

    for (int t = 0; t < NT; ++t) {
        const int cur = t & 1;
        // tile-top c2 prefetch for both subs (hides the ds_read latency
        // under the stage + first MFMA burst; per-sub select is a cndmask)
        const float c2a = c2s[t * 32 + l15];
        const float c2b = c2s[t * 32 + 16 + l15];
        if (t < NT - 1) stage(cur ^ 1, t + 1);

        #pragma unroll
        for (int s = 0; s < 2; ++s) {
            const int sub = s ^ sparity;            // de-phased across blocks
            const int n = t * 32 + sub * 16 + l15;  // this lane's code (col)
            const float c2 = sub ? c2b : c2a;
            f32x4 acc[4];
            #pragma unroll
            for (int g = 0; g < 4; ++g)
                acc[g] = (f32x4){c2, c2, c2, c2};

            #pragma unroll
            for (int f = 0; f < 8; ++f) {
                // B[k=quad*8+j][n=l15]: contiguous 16B/lane, conflict-free
                f16x8 bh = *(const f16x8*)
                    &lbuf[cur * 8192 + sub * 4096 + f * 512 + lane * 8];
                acc[0] = __builtin_amdgcn_mfma_f32_16x16x32_f16(nah[0][f], bh, acc[0], 0, 0, 0);
                acc[1] = __builtin_amdgcn_mfma_f32_16x16x32_f16(nah[1][f], bh, acc[1], 0, 0, 0);
                acc[2] = __builtin_amdgcn_mfma_f32_16x16x32_f16(nah[2][f], bh, acc[2], 0, 0, 0);
                acc[3] = __builtin_amdgcn_mfma_f32_16x16x32_f16(nah[3][f], bh, acc[3], 0, 0, 0);
            }

            #pragma unroll
            for (int g = 0; g < 4; ++g) {
                #pragma unroll
                for (int r = 0; r < 4; ++r) {
                    const int k = (__float_as_int(acc[g][r]) & 0xFFFFFC00) | n;
                    // b2' = median(b1, b2, k)  (valid: b1 <= b2 invariant)
                    int nb2;
                    asm("v_med3_i32 %0, %1, %2, %3"
                        : "=v"(nb2)
                        : "v"(b1[g][r]), "v"(b2[g][r]), "v"(k));
                    b2[g][r] = nb2;
                    b1[g][r] = min(b1[g][r], k);
                }
            }
        }
        __syncthreads();
    }

    // ---- cross-lane top-2 merge: 16 cols live in l15 of each quad ----
    #pragma unroll
    for (int g = 0; g < 4; ++g) {
        #pragma unroll
        for (int r = 0; r < 4; ++r) {
            int x1 = b1[g][r], x2 = b2[g][r];
            #pragma unroll
            for (int off = 8; off > 0; off >>= 1) { // stays in 16-lane group
                int o1 = __shfl_xor(x1, off, 64);
                int o2 = __shfl_xor(x2, off, 64);
                int tt = max(x1, o1);
                x2 = min(min(x2, o2), tt);
                x1 = min(x1, o1);
            }
            if (l15 == 0) {
                const int i1 = x1 & 1023, i2 = x2 & 1023;
                const float s1 = __int_as_float(x1 & 0xFFFFFC00);
                const float s2 = __int_as_float(x2 & 0xFFFFFC00);
                const int row = quad * 4 + r;       // 16x16 C/D row (m89/m91)
                const int slot = g * 16 + row;
                const bool flag = (s2 - s1) < TAU;
                cand[wave * 64 + slot] = i1 | (i2 << 10) | (flag ? (1 << 20) : 0);
                if (!flag) out_idx[p0 + wave * 64 + slot] = (float)i1;
            }
        }
    }

    // ---- sparse exact rescore: lane ℓ owns pixel wave*64 + ℓ ----
    // (cand row is written and read by the SAME wave; compiler-inserted
    // lgkmcnt ordering suffices, as verified in R0/R2/R4/R5/R6)
    const int info = cand[wave * 64 + lane];
    if (info & (1 << 20)) {
        const int i1 = info & 1023, i2 = (info >> 10) & 1023;
        const int p = p0 + wave * 64 + lane;
        const float* xb2 = X + (size_t)(p >> 12) * CHW + (p & 4095);
        const float* r1 = cb + (size_t)i1 * CDIM;
        const float* r2 = cb + (size_t)i2 * CDIM;
        double d1 = 0.0, d2 = 0.0;
        #pragma unroll 4
        for (int d = 0; d < CDIM; d += 4) {
            float x0 = xb2[(size_t)(d + 0) * HW];
            float x1v = xb2[(size_t)(d + 1) * HW];
            float x2v = xb2[(size_t)(d + 2) * HW];
            float x3v = xb2[(size_t)(d + 3) * HW];
            const float4 v1 = *(const float4*)(r1 + d);
            const float4 v2 = *(const float4*)(r2 + d);
            d1 += (double)x0 * v1.x + (double)x1v * v1.y
                + (double)x2v * v1.z + (double)x3v * v1.w;
            d2 += (double)x0 * v2.x + (double)x1v * v2.y
                + (double)x2v * v2.z + (double)x3v * v2.w;
        }
        const double dd1 = c2d[i1] - d1;
        const double dd2 = c2d[i2] - d2;
        const int bi = (dd2 < dd1 || (dd2 == dd1 && i2 < i1)) ? i2 : i1;
        out_idx[p] = (float)bi;
    }
}

// cosine over H: one block per (b,w), one thread per channel c.
__global__ void cosine_kernel(const float* __restrict__ cb,
                              const float* __restrict__ idx_z_f,
                              const float* __restrict__ idx_gt_f,
                              float* __restrict__ out_cos) {
    __shared__ int s_ig[64], s_iq[64];
    const int bw = blockIdx.x;
    const int c = threadIdx.x;
    const int b = bw >> 6, w = bw & 63;
    if (c < 64) {
        s_ig[c] = (int)idx_gt_f[b * 4096 + c * 64 + w];
    } else if (c < 128) {
        int h = c - 64;
        s_iq[h] = (int)idx_z_f[b * 4096 + h * 64 + w];
    }
    __syncthreads();
    float num = 0.f, sa = 0.f, sb = 0.f;
    #pragma unroll 1
    for (int h = 0; h < 64; h += 4) {
        float av[4], bv[4];
        #pragma unroll
        for (int u = 0; u < 4; ++u) {
            av[u] = cb[s_ig[h + u] * CDIM + c];
            bv[u] = cb[s_iq[h + u] * CDIM + c];
        }
        #pragma unroll
        for (int u = 0; u < 4; ++u) {
            num += av[u] * bv[u];
            sa += av[u] * av[u];
            sb += bv[u] * bv[u];
        }
    }
    const float nx = fmaxf(sqrtf(sa), 1e-8f);
    const float ny = fmaxf(sqrtf(sb), 1e-8f);
    out_cos[bw * CDIM + c] = num / (nx * ny);
}

extern "C" void kernel_launch(void* const* d_in, const int* in_sizes, int n_in,
                              void* d_out, int out_size, void* d_ws, size_t ws_size,
                              hipStream_t stream) {
    const float* z  = (const float*)d_in[0];
    const float* gt = (const float*)d_in[1];
    const float* cb = (const float*)d_in[2];
    float* out = (float*)d_out;

    _Float16* hi = (_Float16*)d_ws;
    float*  c2f = (float*)((char*)d_ws + 512 * 1024);
    double* c2d = (double*)((char*)d_ws + 516 * 1024);

    float* out_cos    = out;                   // (16,64,256)
    float* out_idx_gt = out + OUT_COS;         // (65536,1)
    float* out_idx_z  = out + OUT_COS + N_PIX; // (65536,1)

    prep_kernel<<<NE, 64, 0, stream>>>(cb, hi, c2f, c2d);
    argmin_kernel<<<512, 256, 0, stream>>>(z, gt, hi, cb, c2f, c2d,
                                           out_idx_z, out_idx_gt);
    cosine_kernel<<<1024, 256, 0, stream>>>(cb, out_idx_z, out_idx_gt, out_cos);
}